// Round 4
// baseline (8223.228 us; speedup 1.0000x reference)
//
#include <hip/hip_runtime.h>
#include <math.h>

#define NBLK    256
#define NTHR    256
#define HDIM    2048
#define TSTEPS  256
#define BBASIS  8
#define NCNT    64          // packed u32 release counters (256 B)

typedef float f32x4 __attribute__((ext_vector_type(4)));
typedef float f32x2 __attribute__((ext_vector_type(2)));

// Coherent 8B store: bypass L1/L2 (sc0 sc1) so all XCDs see it at Infinity Cache.
__device__ inline void store_coherent_f2(float* p, f32x2 v) {
    asm volatile("global_store_dwordx2 %0, %1, off sc0 sc1"
                 :: "v"(p), "v"(v) : "memory");
}

// Coherent (IC-level) 2x16B load, single wait.
__device__ inline void load_coherent_2xf4(const float* p0, const float* p1,
                                          f32x4& a, f32x4& b) {
    asm volatile(
        "global_load_dwordx4 %0, %2, off sc0 sc1\n\t"
        "global_load_dwordx4 %1, %3, off sc0 sc1\n\t"
        "s_waitcnt vmcnt(0)"
        : "=&v"(a), "=&v"(b)
        : "v"(p0), "v"(p1)
        : "memory");
}

// Persistent-grid Elman scan with counter-released exchange.
// Block owns 8 rows of h; wave w owns rows j0 = bid*8 + 2w, j0+1.
// Lane l covers columns c = 4l + 256k + i (k=0..7, i=0..3) -> float4 index l + 64k.
__global__ __launch_bounds__(NTHR, 1)
void elman_scan_kernel(const float* __restrict__ x,        // [256][2048]
                       const float* __restrict__ W,        // [8][2048][2048]
                       const float* __restrict__ alphas,   // [8][8]
                       const float* __restrict__ bias,     // [2048]
                       const float* __restrict__ v,        // [2048][2048]
                       const float* __restrict__ fc_w,     // [2048][2048]
                       const float* __restrict__ fc_b,     // [2048]
                       const int*   __restrict__ alpha_int,
                       float*       __restrict__ out,      // [2048]
                       unsigned int* __restrict__ cnt,     // [NCNT], zeroed each launch
                       float*       __restrict__ hbuf)     // [TSTEPS+1][2048] fresh slots
{
    const int tid  = threadIdx.x;
    const int bid  = blockIdx.x;
    const int wave = tid >> 6;
    const int lane = tid & 63;
    const int j0   = bid * 8 + wave * 2;   // this wave's two output rows
    const int j1   = j0 + 1;

    __shared__ __align__(16) float h_lds[2][HDIM];       // 16 KB double buffer
    __shared__ float ig_lds[8][TSTEPS];                  // 8 KB igates for this block's rows

    // ---- alpha = softmax(alphas[alpha_int]) (redundant per thread, trivial) ----
    const int ai = alpha_int[0];
    float a[BBASIS];
    float mx = -1e30f;
    #pragma unroll
    for (int b = 0; b < BBASIS; ++b) { a[b] = alphas[ai * BBASIS + b]; mx = fmaxf(mx, a[b]); }
    float ssum = 0.f;
    #pragma unroll
    for (int b = 0; b < BBASIS; ++b) { a[b] = expf(a[b] - mx); ssum += a[b]; }
    const float inv_s = 1.f / ssum;

    // ---- igates: ig_lds[r][t] = dot(x[t,:], v[j,:]) for this wave's 2 rows ----
    {
        float vr[2][8][4];
        #pragma unroll
        for (int j2 = 0; j2 < 2; ++j2) {
            const float4* vrow = (const float4*)(v + (size_t)(j0 + j2) * HDIM);
            #pragma unroll
            for (int k = 0; k < 8; ++k) {
                float4 t4 = vrow[lane + 64 * k];
                vr[j2][k][0] = t4.x; vr[j2][k][1] = t4.y; vr[j2][k][2] = t4.z; vr[j2][k][3] = t4.w;
            }
        }
        for (int t = 0; t < TSTEPS; ++t) {
            const float4* xt = (const float4*)(x + (size_t)t * HDIM);
            float acc0 = 0.f, acc1 = 0.f;
            #pragma unroll
            for (int k = 0; k < 8; ++k) {
                float4 x4 = xt[lane + 64 * k];
                acc0 += vr[0][k][0]*x4.x + vr[0][k][1]*x4.y + vr[0][k][2]*x4.z + vr[0][k][3]*x4.w;
                acc1 += vr[1][k][0]*x4.x + vr[1][k][1]*x4.y + vr[1][k][2]*x4.z + vr[1][k][3]*x4.w;
            }
            #pragma unroll
            for (int off = 32; off > 0; off >>= 1) {
                acc0 += __shfl_xor(acc0, off, 64);
                acc1 += __shfl_xor(acc1, off, 64);
            }
            if (lane == 0) {
                ig_lds[wave * 2 + 0][t] = acc0;
                ig_lds[wave * 2 + 1][t] = acc1;
            }
        }
    }

    // ---- u = sum_b alpha[b] * W[b], rows j0/j1 into registers ----
    float u_reg[2][8][4];
    #pragma unroll
    for (int j2 = 0; j2 < 2; ++j2)
        #pragma unroll
        for (int k = 0; k < 8; ++k)
            #pragma unroll
            for (int i = 0; i < 4; ++i) u_reg[j2][k][i] = 0.f;

    for (int b = 0; b < BBASIS; ++b) {
        const float ab = a[b] * inv_s;
        #pragma unroll
        for (int j2 = 0; j2 < 2; ++j2) {
            const float4* wrow = (const float4*)(W + ((size_t)b * HDIM + (size_t)(j0 + j2)) * HDIM);
            #pragma unroll
            for (int k = 0; k < 8; ++k) {
                float4 w4 = wrow[lane + 64 * k];
                u_reg[j2][k][0] += ab * w4.x;
                u_reg[j2][k][1] += ab * w4.y;
                u_reg[j2][k][2] += ab * w4.z;
                u_reg[j2][k][3] += ab * w4.w;
            }
        }
    }
    const float bias0 = bias[j0], bias1 = bias[j1];

    // ---- h0 = 0 ----
    for (int i = tid; i < HDIM; i += NTHR) h_lds[0][i] = 0.f;
    __syncthreads();

    // Each wave releases into counter (bid*4+wave)&63 -> 16 waves per counter.
    const int my_cnt = (bid * 4 + wave) & (NCNT - 1);

    // ---- sequential scan ----
    int cur = 0;
    for (int t = 0; t < TSTEPS; ++t) {
        float acc0 = 0.f, acc1 = 0.f;
        #pragma unroll
        for (int k = 0; k < 8; ++k) {
            const f32x4 h4 = ((const f32x4*)h_lds[cur])[lane + 64 * k];
            acc0 += u_reg[0][k][0]*h4.x + u_reg[0][k][1]*h4.y + u_reg[0][k][2]*h4.z + u_reg[0][k][3]*h4.w;
            acc1 += u_reg[1][k][0]*h4.x + u_reg[1][k][1]*h4.y + u_reg[1][k][2]*h4.z + u_reg[1][k][3]*h4.w;
        }
        #pragma unroll
        for (int off = 32; off > 0; off >>= 1) {
            acc0 += __shfl_xor(acc0, off, 64);
            acc1 += __shfl_xor(acc1, off, 64);
        }
        float* hg = hbuf + (size_t)(t + 1) * HDIM;
        if (lane == 0) {
            float hn0 = tanhf(acc0 + ig_lds[wave * 2 + 0][t] + bias0);
            float hn1 = tanhf(acc1 + ig_lds[wave * 2 + 1][t] + bias1);
            f32x2 hv; hv.x = hn0; hv.y = hn1;
            store_coherent_f2(&hg[j0], hv);
            // store acked at IC, then release this wave's count
            asm volatile("s_waitcnt vmcnt(0)" ::: "memory");
            __hip_atomic_fetch_add(&cnt[my_cnt], 1u,
                                   __ATOMIC_RELAXED, __HIP_MEMORY_SCOPE_AGENT);
        }
        // wave-wide detect: lane l polls counter l (4 cache lines total per round)
        const unsigned tgt = 16u * (unsigned)(t + 1);
        for (;;) {
            unsigned c;
            asm volatile("global_load_dword %0, %1, off sc0 sc1\n\t"
                         "s_waitcnt vmcnt(0)"
                         : "=v"(c) : "v"(cnt + lane) : "memory");
            if (__ballot(c >= tgt) == ~0ull) break;
            __builtin_amdgcn_s_sleep(1);
        }
        // stage h_{t+1}: exactly one coherent read per thread (32 B)
        f32x4 ha, hb;
        load_coherent_2xf4(hg + 4 * tid, hg + 1024 + 4 * tid, ha, hb);
        const int nxt = cur ^ 1;
        *(f32x4*)&h_lds[nxt][4 * tid]        = ha;
        *(f32x4*)&h_lds[nxt][1024 + 4 * tid] = hb;
        __syncthreads();
        cur = nxt;
    }

    // ---- out = sigmoid(h @ fc_w.T + fc_b) ----
    {
        float acc0 = 0.f, acc1 = 0.f;
        const float4* f0 = (const float4*)(fc_w + (size_t)j0 * HDIM);
        const float4* f1 = (const float4*)(fc_w + (size_t)j1 * HDIM);
        #pragma unroll
        for (int k = 0; k < 8; ++k) {
            const f32x4 h4 = ((const f32x4*)h_lds[cur])[lane + 64 * k];
            float4 w0 = f0[lane + 64 * k];
            float4 w1 = f1[lane + 64 * k];
            acc0 += w0.x*h4.x + w0.y*h4.y + w0.z*h4.z + w0.w*h4.w;
            acc1 += w1.x*h4.x + w1.y*h4.y + w1.z*h4.z + w1.w*h4.w;
        }
        #pragma unroll
        for (int off = 32; off > 0; off >>= 1) {
            acc0 += __shfl_xor(acc0, off, 64);
            acc1 += __shfl_xor(acc1, off, 64);
        }
        if (lane == 0) {
            out[j0] = 1.f / (1.f + expf(-(acc0 + fc_b[j0])));
            out[j1] = 1.f / (1.f + expf(-(acc1 + fc_b[j1])));
        }
    }
}

extern "C" void kernel_launch(void* const* d_in, const int* in_sizes, int n_in,
                              void* d_out, int out_size, void* d_ws, size_t ws_size,
                              hipStream_t stream)
{
    const float* x      = (const float*)d_in[0];
    const float* W      = (const float*)d_in[1];
    const float* alphas = (const float*)d_in[2];
    const float* bias   = (const float*)d_in[3];
    const float* v      = (const float*)d_in[4];
    const float* fc_w   = (const float*)d_in[5];
    const float* fc_b   = (const float*)d_in[6];
    const int*   ai     = (const int*)d_in[7];
    float* out = (float*)d_out;

    unsigned int* cnt  = (unsigned int*)d_ws;             // 256 B counters (4 KB reserved)
    float*        hbuf = (float*)((char*)d_ws + 4096);    // [257][2048] floats, ~2.06 MB

    // Counters must start at 0 every launch (graph replays don't re-poison d_ws).
    // hbuf needs NO reset: every slot is fully written before its counter release.
    hipMemsetAsync(d_ws, 0, 4096, stream);

    elman_scan_kernel<<<NBLK, NTHR, 0, stream>>>(x, W, alphas, bias, v, fc_w, fc_b,
                                                 ai, out, cnt, hbuf);
}

// Round 5
// 1042.635 us; speedup vs baseline: 7.8870x; 7.8870x over previous
//
#include <hip/hip_runtime.h>
#include <math.h>

#define NBLK    64
#define NTHR    512
#define HDIM    2048
#define TSTEPS  256
#define BBASIS  8
#define RPB     32      // rows per block  (HDIM/NBLK)
#define RPW     4       // rows per wave   (RPB/8 waves)
#define TTILE   8       // x timesteps staged in LDS per igates tile

typedef float f32x4 __attribute__((ext_vector_type(4)));

// Coherent 16B store (bypass L1/L2 so all XCDs see it at Infinity Cache).
__device__ inline void store_coherent_f4(float* p, f32x4 v) {
    asm volatile("global_store_dwordx4 %0, %1, off sc0 sc1"
                 :: "v"(p), "v"(v) : "memory");
}

// One coherent 16B poll round.
__device__ inline f32x4 load_coherent_f4(const float* p) {
    f32x4 a;
    asm volatile("global_load_dwordx4 %0, %1, off sc0 sc1\n\t"
                 "s_waitcnt vmcnt(0)"
                 : "=&v"(a) : "v"(p) : "memory");
    return a;
}

// Persistent-grid Elman scan, 64 blocks x 512 threads.
// Block owns 32 rows of h; wave w owns rows r0 = bid*32 + 4w .. r0+3.
// Lane l covers cols c = 4l + 256k (k=0..7) as f32x4 index l + 64k.
__global__ __launch_bounds__(NTHR, 1)
void elman_scan_kernel(const float* __restrict__ x,        // [256][2048]
                       const float* __restrict__ W,        // [8][2048][2048]
                       const float* __restrict__ alphas,   // [8][8]
                       const float* __restrict__ bias,     // [2048]
                       const float* __restrict__ v,        // [2048][2048]
                       const float* __restrict__ fc_w,     // [2048][2048]
                       const float* __restrict__ fc_b,     // [2048]
                       const int*   __restrict__ alpha_int,
                       float*       __restrict__ out,      // [2048]
                       float*       __restrict__ hbuf)     // [TSTEPS+1][2048], 0xFF-filled
{
    const int tid  = threadIdx.x;
    const int bid  = blockIdx.x;
    const int wave = tid >> 6;
    const int lane = tid & 63;
    const int r0   = bid * RPB + wave * RPW;   // this wave's first output row

    __shared__ __align__(16) float x_tile[TTILE][HDIM];   // 64 KB igates staging
    __shared__ __align__(16) float ig_lds[TSTEPS][RPB];   // 32 KB igates (transposed)
    __shared__ __align__(16) float h_lds[2][HDIM];        // 16 KB h double buffer
    __shared__ __align__(16) float hstage[RPB];           // 128 B gather for the h store

    // ---- alpha = softmax(alphas[alpha_int]) (redundant per thread, trivial) ----
    const int ai = alpha_int[0];
    float a[BBASIS];
    float mx = -1e30f;
    #pragma unroll
    for (int b = 0; b < BBASIS; ++b) { a[b] = alphas[ai * BBASIS + b]; mx = fmaxf(mx, a[b]); }
    float ssum = 0.f;
    #pragma unroll
    for (int b = 0; b < BBASIS; ++b) { a[b] = expf(a[b] - mx); ssum += a[b]; }
    const float inv_s = 1.f / ssum;

    // ---- igates: ig_lds[t][r] = dot(x[t,:], v[r,:]) for this wave's 4 rows ----
    {
        float vr[RPW][8][4];                 // 128 VGPRs: v rows r0..r0+3
        #pragma unroll
        for (int q = 0; q < RPW; ++q) {
            const f32x4* vrow = (const f32x4*)(v + (size_t)(r0 + q) * HDIM);
            #pragma unroll
            for (int k = 0; k < 8; ++k) {
                f32x4 t4 = vrow[lane + 64 * k];
                vr[q][k][0] = t4.x; vr[q][k][1] = t4.y; vr[q][k][2] = t4.z; vr[q][k][3] = t4.w;
            }
        }
        for (int tb = 0; tb < TSTEPS; tb += TTILE) {
            // stage 8 x-rows: thread tid copies 16B of each row
            #pragma unroll
            for (int j = 0; j < TTILE; ++j)
                *(f32x4*)&x_tile[j][4 * tid] =
                    *(const f32x4*)&x[(size_t)(tb + j) * HDIM + 4 * tid];
            __syncthreads();
            #pragma unroll
            for (int j = 0; j < TTILE; ++j) {
                float acc0 = 0.f, acc1 = 0.f, acc2 = 0.f, acc3 = 0.f;
                #pragma unroll
                for (int k = 0; k < 8; ++k) {
                    const f32x4 x4 = ((const f32x4*)x_tile[j])[lane + 64 * k];
                    acc0 += vr[0][k][0]*x4.x + vr[0][k][1]*x4.y + vr[0][k][2]*x4.z + vr[0][k][3]*x4.w;
                    acc1 += vr[1][k][0]*x4.x + vr[1][k][1]*x4.y + vr[1][k][2]*x4.z + vr[1][k][3]*x4.w;
                    acc2 += vr[2][k][0]*x4.x + vr[2][k][1]*x4.y + vr[2][k][2]*x4.z + vr[2][k][3]*x4.w;
                    acc3 += vr[3][k][0]*x4.x + vr[3][k][1]*x4.y + vr[3][k][2]*x4.z + vr[3][k][3]*x4.w;
                }
                #pragma unroll
                for (int off = 32; off > 0; off >>= 1) {
                    acc0 += __shfl_xor(acc0, off, 64);
                    acc1 += __shfl_xor(acc1, off, 64);
                    acc2 += __shfl_xor(acc2, off, 64);
                    acc3 += __shfl_xor(acc3, off, 64);
                }
                if (lane == 0) {
                    f32x4 ig4; ig4.x = acc0; ig4.y = acc1; ig4.z = acc2; ig4.w = acc3;
                    *(f32x4*)&ig_lds[tb + j][wave * RPW] = ig4;
                }
            }
            __syncthreads();   // x_tile reuse next tile
        }
    }

    // ---- u = sum_b alpha[b] * W[b], rows r0..r0+3 into registers (128 VGPRs) ----
    float u_reg[RPW][8][4];
    #pragma unroll
    for (int q = 0; q < RPW; ++q)
        #pragma unroll
        for (int k = 0; k < 8; ++k)
            #pragma unroll
            for (int i = 0; i < 4; ++i) u_reg[q][k][i] = 0.f;

    for (int b = 0; b < BBASIS; ++b) {
        const float ab = a[b] * inv_s;
        #pragma unroll
        for (int q = 0; q < RPW; ++q) {
            const f32x4* wrow = (const f32x4*)(W + ((size_t)b * HDIM + (size_t)(r0 + q)) * HDIM);
            #pragma unroll
            for (int k = 0; k < 8; ++k) {
                f32x4 w4 = wrow[lane + 64 * k];
                u_reg[q][k][0] += ab * w4.x;
                u_reg[q][k][1] += ab * w4.y;
                u_reg[q][k][2] += ab * w4.z;
                u_reg[q][k][3] += ab * w4.w;
            }
        }
    }
    float bias4[RPW];
    #pragma unroll
    for (int q = 0; q < RPW; ++q) bias4[q] = bias[r0 + q];

    // ---- h0 = 0 ----
    for (int i = tid; i < HDIM; i += NTHR) h_lds[0][i] = 0.f;
    __syncthreads();

    // ---- sequential scan: fresh hbuf slot per step, data-polling exchange ----
    int cur = 0;
    for (int t = 0; t < TSTEPS; ++t) {
        float acc0 = 0.f, acc1 = 0.f, acc2 = 0.f, acc3 = 0.f;
        #pragma unroll
        for (int k = 0; k < 8; ++k) {
            const f32x4 h4 = ((const f32x4*)h_lds[cur])[lane + 64 * k];
            acc0 += u_reg[0][k][0]*h4.x + u_reg[0][k][1]*h4.y + u_reg[0][k][2]*h4.z + u_reg[0][k][3]*h4.w;
            acc1 += u_reg[1][k][0]*h4.x + u_reg[1][k][1]*h4.y + u_reg[1][k][2]*h4.z + u_reg[1][k][3]*h4.w;
            acc2 += u_reg[2][k][0]*h4.x + u_reg[2][k][1]*h4.y + u_reg[2][k][2]*h4.z + u_reg[2][k][3]*h4.w;
            acc3 += u_reg[3][k][0]*h4.x + u_reg[3][k][1]*h4.y + u_reg[3][k][2]*h4.z + u_reg[3][k][3]*h4.w;
        }
        #pragma unroll
        for (int off = 32; off > 0; off >>= 1) {
            acc0 += __shfl_xor(acc0, off, 64);
            acc1 += __shfl_xor(acc1, off, 64);
            acc2 += __shfl_xor(acc2, off, 64);
            acc3 += __shfl_xor(acc3, off, 64);
        }
        if (lane == 0) {
            const f32x4 ig4 = *(const f32x4*)&ig_lds[t][wave * RPW];
            f32x4 hv;
            hv.x = tanhf(acc0 + ig4.x + bias4[0]);
            hv.y = tanhf(acc1 + ig4.y + bias4[1]);
            hv.z = tanhf(acc2 + ig4.z + bias4[2]);
            hv.w = tanhf(acc3 + ig4.w + bias4[3]);
            *(f32x4*)&hstage[wave * RPW] = hv;
        }
        __syncthreads();   // all 8 waves' hstage in, h_lds[cur] reads done

        float* hg = hbuf + (size_t)(t + 1) * HDIM;
        if (wave == 0 && lane < 8) {
            // one coalesced 128B line store for this block's 32 h values
            f32x4 hv = *(const f32x4*)&hstage[lane * 4];
            store_coherent_f4(hg + bid * RPB + lane * 4, hv);
        }

        // every thread polls its own 16B chunk of h_{t+1}
        const float* pp = hg + 4 * tid;
        f32x4 hq = load_coherent_f4(pp);
        const unsigned s = 0xFFFFFFFFu;
        while ((__float_as_uint(hq.x) == s) | (__float_as_uint(hq.y) == s) |
               (__float_as_uint(hq.z) == s) | (__float_as_uint(hq.w) == s)) {
            __builtin_amdgcn_s_sleep(2);
            hq = load_coherent_f4(pp);
        }
        const int nxt = cur ^ 1;
        *(f32x4*)&h_lds[nxt][4 * tid] = hq;
        __syncthreads();
        cur = nxt;
    }

    // ---- out = sigmoid(h @ fc_w.T + fc_b), rows r0..r0+3 per wave ----
    {
        float acc0 = 0.f, acc1 = 0.f, acc2 = 0.f, acc3 = 0.f;
        const f32x4* f0 = (const f32x4*)(fc_w + (size_t)(r0 + 0) * HDIM);
        const f32x4* f1 = (const f32x4*)(fc_w + (size_t)(r0 + 1) * HDIM);
        const f32x4* f2 = (const f32x4*)(fc_w + (size_t)(r0 + 2) * HDIM);
        const f32x4* f3 = (const f32x4*)(fc_w + (size_t)(r0 + 3) * HDIM);
        #pragma unroll
        for (int k = 0; k < 8; ++k) {
            const f32x4 h4 = ((const f32x4*)h_lds[cur])[lane + 64 * k];
            f32x4 w0 = f0[lane + 64 * k];
            f32x4 w1 = f1[lane + 64 * k];
            f32x4 w2 = f2[lane + 64 * k];
            f32x4 w3 = f3[lane + 64 * k];
            acc0 += w0.x*h4.x + w0.y*h4.y + w0.z*h4.z + w0.w*h4.w;
            acc1 += w1.x*h4.x + w1.y*h4.y + w1.z*h4.z + w1.w*h4.w;
            acc2 += w2.x*h4.x + w2.y*h4.y + w2.z*h4.z + w2.w*h4.w;
            acc3 += w3.x*h4.x + w3.y*h4.y + w3.z*h4.z + w3.w*h4.w;
        }
        #pragma unroll
        for (int off = 32; off > 0; off >>= 1) {
            acc0 += __shfl_xor(acc0, off, 64);
            acc1 += __shfl_xor(acc1, off, 64);
            acc2 += __shfl_xor(acc2, off, 64);
            acc3 += __shfl_xor(acc3, off, 64);
        }
        if (lane == 0) {
            f32x4 o4;
            o4.x = 1.f / (1.f + expf(-(acc0 + fc_b[r0 + 0])));
            o4.y = 1.f / (1.f + expf(-(acc1 + fc_b[r0 + 1])));
            o4.z = 1.f / (1.f + expf(-(acc2 + fc_b[r0 + 2])));
            o4.w = 1.f / (1.f + expf(-(acc3 + fc_b[r0 + 3])));
            *(f32x4*)&out[r0] = o4;
        }
    }
}

extern "C" void kernel_launch(void* const* d_in, const int* in_sizes, int n_in,
                              void* d_out, int out_size, void* d_ws, size_t ws_size,
                              hipStream_t stream)
{
    const float* x      = (const float*)d_in[0];
    const float* W      = (const float*)d_in[1];
    const float* alphas = (const float*)d_in[2];
    const float* bias   = (const float*)d_in[3];
    const float* v      = (const float*)d_in[4];
    const float* fc_w   = (const float*)d_in[5];
    const float* fc_b   = (const float*)d_in[6];
    const int*   ai     = (const int*)d_in[7];
    float* out = (float*)d_out;

    float* hbuf = (float*)d_ws;                       // [257][2048] floats, ~2.06 MB
    const size_t hbuf_bytes = (size_t)(TSTEPS + 1) * HDIM * sizeof(float);

    // Sentinel-fill (0xFF = NaN bit pattern, never a tanh output). Required every
    // launch: graph replays do not re-poison d_ws.
    hipMemsetAsync(d_ws, 0xFF, hbuf_bytes, stream);

    elman_scan_kernel<<<NBLK, NTHR, 0, stream>>>(x, W, alphas, bias, v, fc_w, fc_b,
                                                 ai, out, hbuf);
}

// Round 6
// 1033.450 us; speedup vs baseline: 7.9571x; 1.0089x over previous
//
#include <hip/hip_runtime.h>
#include <math.h>

#define HDIM    2048
#define TSTEPS  256
#define BBASIS  8

typedef float f32x4 __attribute__((ext_vector_type(4)));

// ---------------- coherent (Infinity-Cache level) ops ----------------
__device__ inline void store_coherent_f4(float* p, f32x4 v) {
    asm volatile("global_store_dwordx4 %0, %1, off sc0 sc1"
                 :: "v"(p), "v"(v) : "memory");
}
__device__ inline f32x4 load_coherent_f4(const float* p) {
    f32x4 a;
    asm volatile("global_load_dwordx4 %0, %1, off sc0 sc1\n\t"
                 "s_waitcnt vmcnt(0)"
                 : "=&v"(a) : "v"(p) : "memory");
    return a;
}

// =====================================================================
// PREP kernel: 256 blocks x 256 threads.
// Block b owns rows r = b*8 .. b*8+7; wave w (0..3) owns rows b*8+2w, +1.
// Writes u_g[2048][2048] (mixed recurrent matrix) and ig_g[256][2048]
// (igates, [t][row] layout). Plain stores: kernel-boundary flush makes
// them visible to the scan kernel.
// =====================================================================
__global__ __launch_bounds__(256, 1)
void prep_kernel(const float* __restrict__ x,        // [256][2048]
                 const float* __restrict__ W,        // [8][2048][2048]
                 const float* __restrict__ alphas,   // [8][8]
                 const float* __restrict__ v,        // [2048][2048]
                 const int*   __restrict__ alpha_int,
                 float*       __restrict__ u_g,      // [2048][2048]
                 float*       __restrict__ ig_g)     // [256][2048]
{
    const int tid  = threadIdx.x;
    const int bid  = blockIdx.x;
    const int wave = tid >> 6;
    const int lane = tid & 63;
    const int r0   = bid * 8 + wave * 2;     // this wave's two rows

    __shared__ __align__(16) float x_tile[8][HDIM];   // 64 KB

    // softmax(alphas[alpha_int]) per thread
    const int ai = alpha_int[0];
    float a[BBASIS];
    float mx = -1e30f;
    #pragma unroll
    for (int b = 0; b < BBASIS; ++b) { a[b] = alphas[ai * BBASIS + b]; mx = fmaxf(mx, a[b]); }
    float ssum = 0.f;
    #pragma unroll
    for (int b = 0; b < BBASIS; ++b) { a[b] = expf(a[b] - mx); ssum += a[b]; }
    const float inv_s = 1.f / ssum;

    // ---- u rows r0, r0+1 ----
    {
        float acc[2][8][4];
        #pragma unroll
        for (int q = 0; q < 2; ++q)
            #pragma unroll
            for (int k = 0; k < 8; ++k)
                #pragma unroll
                for (int i = 0; i < 4; ++i) acc[q][k][i] = 0.f;

        for (int b = 0; b < BBASIS; ++b) {
            const float ab = a[b] * inv_s;
            #pragma unroll
            for (int q = 0; q < 2; ++q) {
                const f32x4* wrow = (const f32x4*)(W + ((size_t)b * HDIM + (size_t)(r0 + q)) * HDIM);
                #pragma unroll
                for (int k = 0; k < 8; ++k) {
                    f32x4 w4 = wrow[lane + 64 * k];
                    acc[q][k][0] += ab * w4.x;
                    acc[q][k][1] += ab * w4.y;
                    acc[q][k][2] += ab * w4.z;
                    acc[q][k][3] += ab * w4.w;
                }
            }
        }
        #pragma unroll
        for (int q = 0; q < 2; ++q) {
            f32x4* urow = (f32x4*)(u_g + (size_t)(r0 + q) * HDIM);
            #pragma unroll
            for (int k = 0; k < 8; ++k) {
                f32x4 w4;
                w4.x = acc[q][k][0]; w4.y = acc[q][k][1];
                w4.z = acc[q][k][2]; w4.w = acc[q][k][3];
                urow[lane + 64 * k] = w4;
            }
        }
    }

    // ---- igates rows r0, r0+1 over all t ----
    {
        float vr[2][8][4];
        #pragma unroll
        for (int q = 0; q < 2; ++q) {
            const f32x4* vrow = (const f32x4*)(v + (size_t)(r0 + q) * HDIM);
            #pragma unroll
            for (int k = 0; k < 8; ++k) {
                f32x4 t4 = vrow[lane + 64 * k];
                vr[q][k][0] = t4.x; vr[q][k][1] = t4.y; vr[q][k][2] = t4.z; vr[q][k][3] = t4.w;
            }
        }
        for (int tb = 0; tb < TSTEPS; tb += 8) {
            #pragma unroll
            for (int j = 0; j < 8; ++j) {
                const f32x4* xt4 = (const f32x4*)(x + (size_t)(tb + j) * HDIM);
                #pragma unroll
                for (int c = 0; c < 2; ++c)
                    ((f32x4*)x_tile[j])[tid + 256 * c] = xt4[tid + 256 * c];
            }
            __syncthreads();
            #pragma unroll
            for (int j = 0; j < 8; ++j) {
                float acc0 = 0.f, acc1 = 0.f;
                #pragma unroll
                for (int k = 0; k < 8; ++k) {
                    const f32x4 x4 = ((const f32x4*)x_tile[j])[lane + 64 * k];
                    acc0 += vr[0][k][0]*x4.x + vr[0][k][1]*x4.y + vr[0][k][2]*x4.z + vr[0][k][3]*x4.w;
                    acc1 += vr[1][k][0]*x4.x + vr[1][k][1]*x4.y + vr[1][k][2]*x4.z + vr[1][k][3]*x4.w;
                }
                #pragma unroll
                for (int off = 32; off > 0; off >>= 1) {
                    acc0 += __shfl_xor(acc0, off, 64);
                    acc1 += __shfl_xor(acc1, off, 64);
                }
                if (lane == 0)
                    *(float2*)&ig_g[(size_t)(tb + j) * HDIM + r0] = make_float2(acc0, acc1);
            }
            __syncthreads();
        }
    }
}

// =====================================================================
// SCAN kernel: 64 blocks x 512 threads (persistent, 1 block/CU).
// Block owns 32 rows; wave w owns rows r0 = bid*32+4w .. r0+3.
// u/ig read plainly (prep flushed at boundary); h exchanged via IC
// with sc0/sc1 data-polling on fresh per-step slots.
// =====================================================================
__global__ __launch_bounds__(512, 1)
void scan_kernel(const float* __restrict__ bias,
                 const float* __restrict__ fc_w,
                 const float* __restrict__ fc_b,
                 float*       __restrict__ out,
                 const float* __restrict__ u_g,      // [2048][2048]
                 const float* __restrict__ ig_g,     // [256][2048]
                 float*       __restrict__ hbuf)     // [257][2048], 0xFF-filled
{
    const int tid  = threadIdx.x;
    const int bid  = blockIdx.x;
    const int wave = tid >> 6;
    const int lane = tid & 63;
    const int r0   = bid * 32 + wave * 4;

    __shared__ __align__(16) float h_lds[2][HDIM];      // 16 KB
    __shared__ __align__(16) float ig_lds[TSTEPS][32];  // 32 KB

    // ---- stage this block's igates column [t][bid*32 .. +32] into LDS ----
    #pragma unroll
    for (int i = 0; i < 4; ++i) {
        const int c  = tid + 512 * i;        // 0..2047
        const int t  = c >> 3;
        const int ch = c & 7;
        f32x4 g = *(const f32x4*)&ig_g[(size_t)t * HDIM + bid * 32 + ch * 4];
        *(f32x4*)&ig_lds[t][ch * 4] = g;
    }

    // ---- u rows r0..r0+3 into registers (128 VGPRs) ----
    float u_reg[4][8][4];
    #pragma unroll
    for (int q = 0; q < 4; ++q) {
        const f32x4* urow = (const f32x4*)(u_g + (size_t)(r0 + q) * HDIM);
        #pragma unroll
        for (int k = 0; k < 8; ++k) {
            f32x4 w4 = urow[lane + 64 * k];
            u_reg[q][k][0] = w4.x; u_reg[q][k][1] = w4.y;
            u_reg[q][k][2] = w4.z; u_reg[q][k][3] = w4.w;
        }
    }
    float bias4[4];
    #pragma unroll
    for (int q = 0; q < 4; ++q) bias4[q] = bias[r0 + q];

    // ---- h0 = 0 ----
    h_lds[0][tid]        = 0.f;
    h_lds[0][tid + 512]  = 0.f;
    h_lds[0][tid + 1024] = 0.f;
    h_lds[0][tid + 1536] = 0.f;
    __syncthreads();

    // ---- sequential scan ----
    int cur = 0;
    for (int t = 0; t < TSTEPS; ++t) {
        float acc0 = 0.f, acc1 = 0.f, acc2 = 0.f, acc3 = 0.f;
        #pragma unroll
        for (int k = 0; k < 8; ++k) {
            const f32x4 h4 = ((const f32x4*)h_lds[cur])[lane + 64 * k];
            acc0 += u_reg[0][k][0]*h4.x + u_reg[0][k][1]*h4.y + u_reg[0][k][2]*h4.z + u_reg[0][k][3]*h4.w;
            acc1 += u_reg[1][k][0]*h4.x + u_reg[1][k][1]*h4.y + u_reg[1][k][2]*h4.z + u_reg[1][k][3]*h4.w;
            acc2 += u_reg[2][k][0]*h4.x + u_reg[2][k][1]*h4.y + u_reg[2][k][2]*h4.z + u_reg[2][k][3]*h4.w;
            acc3 += u_reg[3][k][0]*h4.x + u_reg[3][k][1]*h4.y + u_reg[3][k][2]*h4.z + u_reg[3][k][3]*h4.w;
        }
        #pragma unroll
        for (int off = 32; off > 0; off >>= 1) {
            acc0 += __shfl_xor(acc0, off, 64);
            acc1 += __shfl_xor(acc1, off, 64);
            acc2 += __shfl_xor(acc2, off, 64);
            acc3 += __shfl_xor(acc3, off, 64);
        }
        float* hg = hbuf + (size_t)(t + 1) * HDIM;
        // per-wave direct store: no gather, no extra barrier on the chain
        if (lane == 0) {
            const f32x4 ig4 = *(const f32x4*)&ig_lds[t][wave * 4];
            f32x4 hv;
            hv.x = tanhf(acc0 + ig4.x + bias4[0]);
            hv.y = tanhf(acc1 + ig4.y + bias4[1]);
            hv.z = tanhf(acc2 + ig4.z + bias4[2]);
            hv.w = tanhf(acc3 + ig4.w + bias4[3]);
            store_coherent_f4(hg + r0, hv);
        }
        // poll own 16B chunk of h_{t+1}
        const float* pp = hg + 4 * tid;
        f32x4 hq = load_coherent_f4(pp);
        const unsigned s = 0xFFFFFFFFu;
        while ((__float_as_uint(hq.x) == s) | (__float_as_uint(hq.y) == s) |
               (__float_as_uint(hq.z) == s) | (__float_as_uint(hq.w) == s)) {
            __builtin_amdgcn_s_sleep(1);
            hq = load_coherent_f4(pp);
        }
        const int nxt = cur ^ 1;
        *(f32x4*)&h_lds[nxt][4 * tid] = hq;
        __syncthreads();
        cur = nxt;
    }

    // ---- out = sigmoid(h @ fc_w.T + fc_b), 4 rows per wave ----
    {
        float acc0 = 0.f, acc1 = 0.f, acc2 = 0.f, acc3 = 0.f;
        const f32x4* f0 = (const f32x4*)(fc_w + (size_t)(r0 + 0) * HDIM);
        const f32x4* f1 = (const f32x4*)(fc_w + (size_t)(r0 + 1) * HDIM);
        const f32x4* f2 = (const f32x4*)(fc_w + (size_t)(r0 + 2) * HDIM);
        const f32x4* f3 = (const f32x4*)(fc_w + (size_t)(r0 + 3) * HDIM);
        #pragma unroll
        for (int k = 0; k < 8; ++k) {
            const f32x4 h4 = ((const f32x4*)h_lds[cur])[lane + 64 * k];
            f32x4 w0 = f0[lane + 64 * k];
            f32x4 w1 = f1[lane + 64 * k];
            f32x4 w2 = f2[lane + 64 * k];
            f32x4 w3 = f3[lane + 64 * k];
            acc0 += w0.x*h4.x + w0.y*h4.y + w0.z*h4.z + w0.w*h4.w;
            acc1 += w1.x*h4.x + w1.y*h4.y + w1.z*h4.z + w1.w*h4.w;
            acc2 += w2.x*h4.x + w2.y*h4.y + w2.z*h4.z + w2.w*h4.w;
            acc3 += w3.x*h4.x + w3.y*h4.y + w3.z*h4.z + w3.w*h4.w;
        }
        #pragma unroll
        for (int off = 32; off > 0; off >>= 1) {
            acc0 += __shfl_xor(acc0, off, 64);
            acc1 += __shfl_xor(acc1, off, 64);
            acc2 += __shfl_xor(acc2, off, 64);
            acc3 += __shfl_xor(acc3, off, 64);
        }
        if (lane == 0) {
            f32x4 o4;
            o4.x = 1.f / (1.f + expf(-(acc0 + fc_b[r0 + 0])));
            o4.y = 1.f / (1.f + expf(-(acc1 + fc_b[r0 + 1])));
            o4.z = 1.f / (1.f + expf(-(acc2 + fc_b[r0 + 2])));
            o4.w = 1.f / (1.f + expf(-(acc3 + fc_b[r0 + 3])));
            *(f32x4*)&out[r0] = o4;
        }
    }
}

// =====================================================================
// FALLBACK: R5 single kernel (self-contained), used when ws too small.
// =====================================================================
__global__ __launch_bounds__(512, 1)
void elman_scan_self(const float* __restrict__ x,
                     const float* __restrict__ W,
                     const float* __restrict__ alphas,
                     const float* __restrict__ bias,
                     const float* __restrict__ v,
                     const float* __restrict__ fc_w,
                     const float* __restrict__ fc_b,
                     const int*   __restrict__ alpha_int,
                     float*       __restrict__ out,
                     float*       __restrict__ hbuf)
{
    const int tid  = threadIdx.x;
    const int bid  = blockIdx.x;
    const int wave = tid >> 6;
    const int lane = tid & 63;
    const int r0   = bid * 32 + wave * 4;

    __shared__ __align__(16) float x_tile[8][HDIM];
    __shared__ __align__(16) float ig_lds[TSTEPS][32];
    __shared__ __align__(16) float h_lds[2][HDIM];

    const int ai = alpha_int[0];
    float a[BBASIS];
    float mx = -1e30f;
    #pragma unroll
    for (int b = 0; b < BBASIS; ++b) { a[b] = alphas[ai * BBASIS + b]; mx = fmaxf(mx, a[b]); }
    float ssum = 0.f;
    #pragma unroll
    for (int b = 0; b < BBASIS; ++b) { a[b] = expf(a[b] - mx); ssum += a[b]; }
    const float inv_s = 1.f / ssum;

    {
        float vr[4][8][4];
        #pragma unroll
        for (int q = 0; q < 4; ++q) {
            const f32x4* vrow = (const f32x4*)(v + (size_t)(r0 + q) * HDIM);
            #pragma unroll
            for (int k = 0; k < 8; ++k) {
                f32x4 t4 = vrow[lane + 64 * k];
                vr[q][k][0] = t4.x; vr[q][k][1] = t4.y; vr[q][k][2] = t4.z; vr[q][k][3] = t4.w;
            }
        }
        for (int tb = 0; tb < TSTEPS; tb += 8) {
            #pragma unroll
            for (int j = 0; j < 8; ++j)
                *(f32x4*)&x_tile[j][4 * tid] =
                    *(const f32x4*)&x[(size_t)(tb + j) * HDIM + 4 * tid];
            __syncthreads();
            #pragma unroll
            for (int j = 0; j < 8; ++j) {
                float acc0 = 0.f, acc1 = 0.f, acc2 = 0.f, acc3 = 0.f;
                #pragma unroll
                for (int k = 0; k < 8; ++k) {
                    const f32x4 x4 = ((const f32x4*)x_tile[j])[lane + 64 * k];
                    acc0 += vr[0][k][0]*x4.x + vr[0][k][1]*x4.y + vr[0][k][2]*x4.z + vr[0][k][3]*x4.w;
                    acc1 += vr[1][k][0]*x4.x + vr[1][k][1]*x4.y + vr[1][k][2]*x4.z + vr[1][k][3]*x4.w;
                    acc2 += vr[2][k][0]*x4.x + vr[2][k][1]*x4.y + vr[2][k][2]*x4.z + vr[2][k][3]*x4.w;
                    acc3 += vr[3][k][0]*x4.x + vr[3][k][1]*x4.y + vr[3][k][2]*x4.z + vr[3][k][3]*x4.w;
                }
                #pragma unroll
                for (int off = 32; off > 0; off >>= 1) {
                    acc0 += __shfl_xor(acc0, off, 64);
                    acc1 += __shfl_xor(acc1, off, 64);
                    acc2 += __shfl_xor(acc2, off, 64);
                    acc3 += __shfl_xor(acc3, off, 64);
                }
                if (lane == 0) {
                    f32x4 ig4; ig4.x = acc0; ig4.y = acc1; ig4.z = acc2; ig4.w = acc3;
                    *(f32x4*)&ig_lds[tb + j][wave * 4] = ig4;
                }
            }
            __syncthreads();
        }
    }

    float u_reg[4][8][4];
    #pragma unroll
    for (int q = 0; q < 4; ++q)
        #pragma unroll
        for (int k = 0; k < 8; ++k)
            #pragma unroll
            for (int i = 0; i < 4; ++i) u_reg[q][k][i] = 0.f;

    for (int b = 0; b < BBASIS; ++b) {
        const float ab = a[b] * inv_s;
        #pragma unroll
        for (int q = 0; q < 4; ++q) {
            const f32x4* wrow = (const f32x4*)(W + ((size_t)b * HDIM + (size_t)(r0 + q)) * HDIM);
            #pragma unroll
            for (int k = 0; k < 8; ++k) {
                f32x4 w4 = wrow[lane + 64 * k];
                u_reg[q][k][0] += ab * w4.x;
                u_reg[q][k][1] += ab * w4.y;
                u_reg[q][k][2] += ab * w4.z;
                u_reg[q][k][3] += ab * w4.w;
            }
        }
    }
    float bias4[4];
    #pragma unroll
    for (int q = 0; q < 4; ++q) bias4[q] = bias[r0 + q];

    h_lds[0][tid] = 0.f; h_lds[0][tid + 512] = 0.f;
    h_lds[0][tid + 1024] = 0.f; h_lds[0][tid + 1536] = 0.f;
    __syncthreads();

    int cur = 0;
    for (int t = 0; t < TSTEPS; ++t) {
        float acc0 = 0.f, acc1 = 0.f, acc2 = 0.f, acc3 = 0.f;
        #pragma unroll
        for (int k = 0; k < 8; ++k) {
            const f32x4 h4 = ((const f32x4*)h_lds[cur])[lane + 64 * k];
            acc0 += u_reg[0][k][0]*h4.x + u_reg[0][k][1]*h4.y + u_reg[0][k][2]*h4.z + u_reg[0][k][3]*h4.w;
            acc1 += u_reg[1][k][0]*h4.x + u_reg[1][k][1]*h4.y + u_reg[1][k][2]*h4.z + u_reg[1][k][3]*h4.w;
            acc2 += u_reg[2][k][0]*h4.x + u_reg[2][k][1]*h4.y + u_reg[2][k][2]*h4.z + u_reg[2][k][3]*h4.w;
            acc3 += u_reg[3][k][0]*h4.x + u_reg[3][k][1]*h4.y + u_reg[3][k][2]*h4.z + u_reg[3][k][3]*h4.w;
        }
        #pragma unroll
        for (int off = 32; off > 0; off >>= 1) {
            acc0 += __shfl_xor(acc0, off, 64);
            acc1 += __shfl_xor(acc1, off, 64);
            acc2 += __shfl_xor(acc2, off, 64);
            acc3 += __shfl_xor(acc3, off, 64);
        }
        float* hg = hbuf + (size_t)(t + 1) * HDIM;
        if (lane == 0) {
            const f32x4 ig4 = *(const f32x4*)&ig_lds[t][wave * 4];
            f32x4 hv;
            hv.x = tanhf(acc0 + ig4.x + bias4[0]);
            hv.y = tanhf(acc1 + ig4.y + bias4[1]);
            hv.z = tanhf(acc2 + ig4.z + bias4[2]);
            hv.w = tanhf(acc3 + ig4.w + bias4[3]);
            store_coherent_f4(hg + r0, hv);
        }
        const float* pp = hg + 4 * tid;
        f32x4 hq = load_coherent_f4(pp);
        const unsigned s = 0xFFFFFFFFu;
        while ((__float_as_uint(hq.x) == s) | (__float_as_uint(hq.y) == s) |
               (__float_as_uint(hq.z) == s) | (__float_as_uint(hq.w) == s)) {
            __builtin_amdgcn_s_sleep(1);
            hq = load_coherent_f4(pp);
        }
        const int nxt = cur ^ 1;
        *(f32x4*)&h_lds[nxt][4 * tid] = hq;
        __syncthreads();
        cur = nxt;
    }

    {
        float acc0 = 0.f, acc1 = 0.f, acc2 = 0.f, acc3 = 0.f;
        const f32x4* f0 = (const f32x4*)(fc_w + (size_t)(r0 + 0) * HDIM);
        const f32x4* f1 = (const f32x4*)(fc_w + (size_t)(r0 + 1) * HDIM);
        const f32x4* f2 = (const f32x4*)(fc_w + (size_t)(r0 + 2) * HDIM);
        const f32x4* f3 = (const f32x4*)(fc_w + (size_t)(r0 + 3) * HDIM);
        #pragma unroll
        for (int k = 0; k < 8; ++k) {
            const f32x4 h4 = ((const f32x4*)h_lds[cur])[lane + 64 * k];
            f32x4 w0 = f0[lane + 64 * k];
            f32x4 w1 = f1[lane + 64 * k];
            f32x4 w2 = f2[lane + 64 * k];
            f32x4 w3 = f3[lane + 64 * k];
            acc0 += w0.x*h4.x + w0.y*h4.y + w0.z*h4.z + w0.w*h4.w;
            acc1 += w1.x*h4.x + w1.y*h4.y + w1.z*h4.z + w1.w*h4.w;
            acc2 += w2.x*h4.x + w2.y*h4.y + w2.z*h4.z + w2.w*h4.w;
            acc3 += w3.x*h4.x + w3.y*h4.y + w3.z*h4.z + w3.w*h4.w;
        }
        #pragma unroll
        for (int off = 32; off > 0; off >>= 1) {
            acc0 += __shfl_xor(acc0, off, 64);
            acc1 += __shfl_xor(acc1, off, 64);
            acc2 += __shfl_xor(acc2, off, 64);
            acc3 += __shfl_xor(acc3, off, 64);
        }
        if (lane == 0) {
            f32x4 o4;
            o4.x = 1.f / (1.f + expf(-(acc0 + fc_b[r0 + 0])));
            o4.y = 1.f / (1.f + expf(-(acc1 + fc_b[r0 + 1])));
            o4.z = 1.f / (1.f + expf(-(acc2 + fc_b[r0 + 2])));
            o4.w = 1.f / (1.f + expf(-(acc3 + fc_b[r0 + 3])));
            *(f32x4*)&out[r0] = o4;
        }
    }
}

extern "C" void kernel_launch(void* const* d_in, const int* in_sizes, int n_in,
                              void* d_out, int out_size, void* d_ws, size_t ws_size,
                              hipStream_t stream)
{
    const float* x      = (const float*)d_in[0];
    const float* W      = (const float*)d_in[1];
    const float* alphas = (const float*)d_in[2];
    const float* bias   = (const float*)d_in[3];
    const float* v      = (const float*)d_in[4];
    const float* fc_w   = (const float*)d_in[5];
    const float* fc_b   = (const float*)d_in[6];
    const int*   ai     = (const int*)d_in[7];
    float* out = (float*)d_out;

    // workspace layout
    const size_t HB_BYTES = (size_t)(TSTEPS + 1) * HDIM * sizeof(float);  // 2,105,344
    const size_t IG_OFF   = 0x210000;                                      // 2,162,688
    const size_t IG_BYTES = (size_t)TSTEPS * HDIM * sizeof(float);         // 2,097,152
    const size_t U_OFF    = IG_OFF + 0x210000;                             // 4,325,376
    const size_t U_BYTES  = (size_t)HDIM * HDIM * sizeof(float);           // 16,777,216
    const size_t NEED     = U_OFF + U_BYTES;

    float* hbuf = (float*)d_ws;

    // Sentinel-fill hbuf every launch (0xFF = NaN pattern, never a tanh output).
    hipMemsetAsync(d_ws, 0xFF, HB_BYTES, stream);

    if (ws_size >= NEED) {
        float* ig_g = (float*)((char*)d_ws + IG_OFF);
        float* u_g  = (float*)((char*)d_ws + U_OFF);
        prep_kernel<<<256, 256, 0, stream>>>(x, W, alphas, v, ai, u_g, ig_g);
        scan_kernel<<<64, 512, 0, stream>>>(bias, fc_w, fc_b, out, u_g, ig_g, hbuf);
    } else {
        elman_scan_self<<<64, 512, 0, stream>>>(x, W, alphas, bias, v, fc_w, fc_b,
                                                ai, out, hbuf);
    }
}

// Round 7
// 995.472 us; speedup vs baseline: 8.2606x; 1.0382x over previous
//
#include <hip/hip_runtime.h>
#include <math.h>

#define HDIM    2048
#define TSTEPS  256
#define BBASIS  8
#define RING_D  4          // ring depth (slots reused mod 4; safe: readers done at st-2)
#define NR      8          // replicas per slot; block b polls replica b&7

typedef float f32x4 __attribute__((ext_vector_type(4)));

// ---------------- coherent (Infinity-Cache level) ops ----------------
__device__ inline void store_coherent_f4(float* p, f32x4 v) {
    asm volatile("global_store_dwordx4 %0, %1, off sc0 sc1"
                 :: "v"(p), "v"(v) : "memory");
}
__device__ inline f32x4 load_coherent_f4(const float* p) {
    f32x4 a;
    asm volatile("global_load_dwordx4 %0, %1, off sc0 sc1\n\t"
                 "s_waitcnt vmcnt(0)"
                 : "=&v"(a) : "v"(p) : "memory");
    return a;
}

// =====================================================================
// PREP kernel: 256 blocks x 256 threads (unchanged from R6).
// Block b owns rows r = b*8 .. b*8+7; wave w (0..3) owns rows b*8+2w, +1.
// Writes u_g[2048][2048] and ig_g[256][2048]. Plain stores: kernel-boundary
// flush makes them visible to the scan kernel.
// =====================================================================
__global__ __launch_bounds__(256, 1)
void prep_kernel(const float* __restrict__ x,        // [256][2048]
                 const float* __restrict__ W,        // [8][2048][2048]
                 const float* __restrict__ alphas,   // [8][8]
                 const float* __restrict__ v,        // [2048][2048]
                 const int*   __restrict__ alpha_int,
                 float*       __restrict__ u_g,      // [2048][2048]
                 float*       __restrict__ ig_g)     // [256][2048]
{
    const int tid  = threadIdx.x;
    const int bid  = blockIdx.x;
    const int wave = tid >> 6;
    const int lane = tid & 63;
    const int r0   = bid * 8 + wave * 2;     // this wave's two rows

    __shared__ __align__(16) float x_tile[8][HDIM];   // 64 KB

    const int ai = alpha_int[0];
    float a[BBASIS];
    float mx = -1e30f;
    #pragma unroll
    for (int b = 0; b < BBASIS; ++b) { a[b] = alphas[ai * BBASIS + b]; mx = fmaxf(mx, a[b]); }
    float ssum = 0.f;
    #pragma unroll
    for (int b = 0; b < BBASIS; ++b) { a[b] = expf(a[b] - mx); ssum += a[b]; }
    const float inv_s = 1.f / ssum;

    // ---- u rows r0, r0+1 ----
    {
        float acc[2][8][4];
        #pragma unroll
        for (int q = 0; q < 2; ++q)
            #pragma unroll
            for (int k = 0; k < 8; ++k)
                #pragma unroll
                for (int i = 0; i < 4; ++i) acc[q][k][i] = 0.f;

        for (int b = 0; b < BBASIS; ++b) {
            const float ab = a[b] * inv_s;
            #pragma unroll
            for (int q = 0; q < 2; ++q) {
                const f32x4* wrow = (const f32x4*)(W + ((size_t)b * HDIM + (size_t)(r0 + q)) * HDIM);
                #pragma unroll
                for (int k = 0; k < 8; ++k) {
                    f32x4 w4 = wrow[lane + 64 * k];
                    acc[q][k][0] += ab * w4.x;
                    acc[q][k][1] += ab * w4.y;
                    acc[q][k][2] += ab * w4.z;
                    acc[q][k][3] += ab * w4.w;
                }
            }
        }
        #pragma unroll
        for (int q = 0; q < 2; ++q) {
            f32x4* urow = (f32x4*)(u_g + (size_t)(r0 + q) * HDIM);
            #pragma unroll
            for (int k = 0; k < 8; ++k) {
                f32x4 w4;
                w4.x = acc[q][k][0]; w4.y = acc[q][k][1];
                w4.z = acc[q][k][2]; w4.w = acc[q][k][3];
                urow[lane + 64 * k] = w4;
            }
        }
    }

    // ---- igates rows r0, r0+1 over all t ----
    {
        float vr[2][8][4];
        #pragma unroll
        for (int q = 0; q < 2; ++q) {
            const f32x4* vrow = (const f32x4*)(v + (size_t)(r0 + q) * HDIM);
            #pragma unroll
            for (int k = 0; k < 8; ++k) {
                f32x4 t4 = vrow[lane + 64 * k];
                vr[q][k][0] = t4.x; vr[q][k][1] = t4.y; vr[q][k][2] = t4.z; vr[q][k][3] = t4.w;
            }
        }
        for (int tb = 0; tb < TSTEPS; tb += 8) {
            #pragma unroll
            for (int j = 0; j < 8; ++j) {
                const f32x4* xt4 = (const f32x4*)(x + (size_t)(tb + j) * HDIM);
                #pragma unroll
                for (int c = 0; c < 2; ++c)
                    ((f32x4*)x_tile[j])[tid + 256 * c] = xt4[tid + 256 * c];
            }
            __syncthreads();
            #pragma unroll
            for (int j = 0; j < 8; ++j) {
                float acc0 = 0.f, acc1 = 0.f;
                #pragma unroll
                for (int k = 0; k < 8; ++k) {
                    const f32x4 x4 = ((const f32x4*)x_tile[j])[lane + 64 * k];
                    acc0 += vr[0][k][0]*x4.x + vr[0][k][1]*x4.y + vr[0][k][2]*x4.z + vr[0][k][3]*x4.w;
                    acc1 += vr[1][k][0]*x4.x + vr[1][k][1]*x4.y + vr[1][k][2]*x4.z + vr[1][k][3]*x4.w;
                }
                #pragma unroll
                for (int off = 32; off > 0; off >>= 1) {
                    acc0 += __shfl_xor(acc0, off, 64);
                    acc1 += __shfl_xor(acc1, off, 64);
                }
                if (lane == 0)
                    *(float2*)&ig_g[(size_t)(tb + j) * HDIM + r0] = make_float2(acc0, acc1);
            }
            __syncthreads();
        }
    }
}

// =====================================================================
// SCAN kernel: 64 blocks x 512 threads (persistent, 1 block/CU).
// Ring exchange: slot = st & 3, 8 replicas/slot, band-bias parity tags.
// Producer wave: butterfly leaves sums in ALL lanes; all lanes compute
// tanh(+bias); lanes 0..7 store the 16B to the 8 replicas (one VMEM op).
// Consumer: block polls ONLY replica bid&7 -> 8x fewer readers per line.
// =====================================================================
__global__ __launch_bounds__(512, 1)
void scan_kernel(const float* __restrict__ bias,
                 const float* __restrict__ fc_w,
                 const float* __restrict__ fc_b,
                 float*       __restrict__ out,
                 const float* __restrict__ u_g,      // [2048][2048]
                 const float* __restrict__ ig_g,     // [256][2048]
                 float*       __restrict__ ring)     // [RING_D][NR][2048], zeroed
{
    const int tid  = threadIdx.x;
    const int bid  = blockIdx.x;
    const int wave = tid >> 6;
    const int lane = tid & 63;
    const int r0   = bid * 32 + wave * 4;

    __shared__ __align__(16) float h_lds[2][HDIM];      // 16 KB
    __shared__ __align__(16) float ig_lds[TSTEPS][32];  // 32 KB

    // ---- stage this block's igates column [t][bid*32 .. +32] into LDS ----
    #pragma unroll
    for (int i = 0; i < 4; ++i) {
        const int c  = tid + 512 * i;        // 0..2047
        const int t  = c >> 3;
        const int ch = c & 7;
        f32x4 g = *(const f32x4*)&ig_g[(size_t)t * HDIM + bid * 32 + ch * 4];
        *(f32x4*)&ig_lds[t][ch * 4] = g;
    }

    // ---- u rows r0..r0+3 into registers (128 VGPRs) ----
    float u_reg[4][8][4];
    #pragma unroll
    for (int q = 0; q < 4; ++q) {
        const f32x4* urow = (const f32x4*)(u_g + (size_t)(r0 + q) * HDIM);
        #pragma unroll
        for (int k = 0; k < 8; ++k) {
            f32x4 w4 = urow[lane + 64 * k];
            u_reg[q][k][0] = w4.x; u_reg[q][k][1] = w4.y;
            u_reg[q][k][2] = w4.z; u_reg[q][k][3] = w4.w;
        }
    }
    float bias4[4];
    #pragma unroll
    for (int q = 0; q < 4; ++q) bias4[q] = bias[r0 + q];

    // ---- h0 = 0 ----
    h_lds[0][tid]        = 0.f;
    h_lds[0][tid + 512]  = 0.f;
    h_lds[0][tid + 1024] = 0.f;
    h_lds[0][tid + 1536] = 0.f;
    __syncthreads();

    // ---- sequential scan ----
    int cur = 0;
    for (int t = 0; t < TSTEPS; ++t) {
        float acc0 = 0.f, acc1 = 0.f, acc2 = 0.f, acc3 = 0.f;
        #pragma unroll
        for (int k = 0; k < 8; ++k) {
            const f32x4 h4 = ((const f32x4*)h_lds[cur])[lane + 64 * k];
            acc0 += u_reg[0][k][0]*h4.x + u_reg[0][k][1]*h4.y + u_reg[0][k][2]*h4.z + u_reg[0][k][3]*h4.w;
            acc1 += u_reg[1][k][0]*h4.x + u_reg[1][k][1]*h4.y + u_reg[1][k][2]*h4.z + u_reg[1][k][3]*h4.w;
            acc2 += u_reg[2][k][0]*h4.x + u_reg[2][k][1]*h4.y + u_reg[2][k][2]*h4.z + u_reg[2][k][3]*h4.w;
            acc3 += u_reg[3][k][0]*h4.x + u_reg[3][k][1]*h4.y + u_reg[3][k][2]*h4.z + u_reg[3][k][3]*h4.w;
        }
        #pragma unroll
        for (int off = 32; off > 0; off >>= 1) {
            acc0 += __shfl_xor(acc0, off, 64);   // butterfly: sums end up in ALL lanes
            acc1 += __shfl_xor(acc1, off, 64);
            acc2 += __shfl_xor(acc2, off, 64);
            acc3 += __shfl_xor(acc3, off, 64);
        }
        const int   st     = t + 1;
        const float bias_f = ((st >> 2) & 1) ? 8.0f : -8.0f;   // parity band tag
        float* slotbase = ring + (size_t)((st & (RING_D - 1)) * NR) * HDIM;

        // all lanes compute identical tanh+bias (same wall time as lane0 alone)
        const f32x4 ig4 = *(const f32x4*)&ig_lds[t][wave * 4];  // LDS broadcast
        f32x4 hv;
        hv.x = tanhf(acc0 + ig4.x + bias4[0]) + bias_f;
        hv.y = tanhf(acc1 + ig4.y + bias4[1]) + bias_f;
        hv.z = tanhf(acc2 + ig4.z + bias4[2]) + bias_f;
        hv.w = tanhf(acc3 + ig4.w + bias4[3]) + bias_f;
        // one VMEM instruction: lanes 0..7 store to the 8 replicas
        if (lane < NR)
            store_coherent_f4(slotbase + (size_t)lane * HDIM + r0, hv);

        // poll own 16B chunk of own replica; band check = arrival signal
        const float* pp = slotbase + (size_t)(bid & (NR - 1)) * HDIM + 4 * tid;
        f32x4 hq = load_coherent_f4(pp);
        if (bias_f > 0.0f) {
            while (!((hq.x > 6.5f) & (hq.y > 6.5f) & (hq.z > 6.5f) & (hq.w > 6.5f))) {
                __builtin_amdgcn_s_sleep(1);
                hq = load_coherent_f4(pp);
            }
        } else {
            while (!((hq.x < -6.5f) & (hq.y < -6.5f) & (hq.z < -6.5f) & (hq.w < -6.5f))) {
                __builtin_amdgcn_s_sleep(1);
                hq = load_coherent_f4(pp);
            }
        }
        hq.x -= bias_f; hq.y -= bias_f; hq.z -= bias_f; hq.w -= bias_f;  // exact (Sterbenz)

        const int nxt = cur ^ 1;
        *(f32x4*)&h_lds[nxt][4 * tid] = hq;
        __syncthreads();
        cur = nxt;
    }

    // ---- out = sigmoid(h @ fc_w.T + fc_b), 4 rows per wave ----
    {
        float acc0 = 0.f, acc1 = 0.f, acc2 = 0.f, acc3 = 0.f;
        const f32x4* f0 = (const f32x4*)(fc_w + (size_t)(r0 + 0) * HDIM);
        const f32x4* f1 = (const f32x4*)(fc_w + (size_t)(r0 + 1) * HDIM);
        const f32x4* f2 = (const f32x4*)(fc_w + (size_t)(r0 + 2) * HDIM);
        const f32x4* f3 = (const f32x4*)(fc_w + (size_t)(r0 + 3) * HDIM);
        #pragma unroll
        for (int k = 0; k < 8; ++k) {
            const f32x4 h4 = ((const f32x4*)h_lds[cur])[lane + 64 * k];
            f32x4 w0 = f0[lane + 64 * k];
            f32x4 w1 = f1[lane + 64 * k];
            f32x4 w2 = f2[lane + 64 * k];
            f32x4 w3 = f3[lane + 64 * k];
            acc0 += w0.x*h4.x + w0.y*h4.y + w0.z*h4.z + w0.w*h4.w;
            acc1 += w1.x*h4.x + w1.y*h4.y + w1.z*h4.z + w1.w*h4.w;
            acc2 += w2.x*h4.x + w2.y*h4.y + w2.z*h4.z + w2.w*h4.w;
            acc3 += w3.x*h4.x + w3.y*h4.y + w3.z*h4.z + w3.w*h4.w;
        }
        #pragma unroll
        for (int off = 32; off > 0; off >>= 1) {
            acc0 += __shfl_xor(acc0, off, 64);
            acc1 += __shfl_xor(acc1, off, 64);
            acc2 += __shfl_xor(acc2, off, 64);
            acc3 += __shfl_xor(acc3, off, 64);
        }
        if (lane == 0) {
            f32x4 o4;
            o4.x = 1.f / (1.f + expf(-(acc0 + fc_b[r0 + 0])));
            o4.y = 1.f / (1.f + expf(-(acc1 + fc_b[r0 + 1])));
            o4.z = 1.f / (1.f + expf(-(acc2 + fc_b[r0 + 2])));
            o4.w = 1.f / (1.f + expf(-(acc3 + fc_b[r0 + 3])));
            *(f32x4*)&out[r0] = o4;
        }
    }
}

// =====================================================================
// FALLBACK: R5 single kernel (sentinel-poll, fresh slots), ws-small path.
// =====================================================================
__global__ __launch_bounds__(512, 1)
void elman_scan_self(const float* __restrict__ x,
                     const float* __restrict__ W,
                     const float* __restrict__ alphas,
                     const float* __restrict__ bias,
                     const float* __restrict__ v,
                     const float* __restrict__ fc_w,
                     const float* __restrict__ fc_b,
                     const int*   __restrict__ alpha_int,
                     float*       __restrict__ out,
                     float*       __restrict__ hbuf)
{
    const int tid  = threadIdx.x;
    const int bid  = blockIdx.x;
    const int wave = tid >> 6;
    const int lane = tid & 63;
    const int r0   = bid * 32 + wave * 4;

    __shared__ __align__(16) float x_tile[8][HDIM];
    __shared__ __align__(16) float ig_lds[TSTEPS][32];
    __shared__ __align__(16) float h_lds[2][HDIM];

    const int ai = alpha_int[0];
    float a[BBASIS];
    float mx = -1e30f;
    #pragma unroll
    for (int b = 0; b < BBASIS; ++b) { a[b] = alphas[ai * BBASIS + b]; mx = fmaxf(mx, a[b]); }
    float ssum = 0.f;
    #pragma unroll
    for (int b = 0; b < BBASIS; ++b) { a[b] = expf(a[b] - mx); ssum += a[b]; }
    const float inv_s = 1.f / ssum;

    {
        float vr[4][8][4];
        #pragma unroll
        for (int q = 0; q < 4; ++q) {
            const f32x4* vrow = (const f32x4*)(v + (size_t)(r0 + q) * HDIM);
            #pragma unroll
            for (int k = 0; k < 8; ++k) {
                f32x4 t4 = vrow[lane + 64 * k];
                vr[q][k][0] = t4.x; vr[q][k][1] = t4.y; vr[q][k][2] = t4.z; vr[q][k][3] = t4.w;
            }
        }
        for (int tb = 0; tb < TSTEPS; tb += 8) {
            #pragma unroll
            for (int j = 0; j < 8; ++j)
                *(f32x4*)&x_tile[j][4 * tid] =
                    *(const f32x4*)&x[(size_t)(tb + j) * HDIM + 4 * tid];
            __syncthreads();
            #pragma unroll
            for (int j = 0; j < 8; ++j) {
                float acc0 = 0.f, acc1 = 0.f, acc2 = 0.f, acc3 = 0.f;
                #pragma unroll
                for (int k = 0; k < 8; ++k) {
                    const f32x4 x4 = ((const f32x4*)x_tile[j])[lane + 64 * k];
                    acc0 += vr[0][k][0]*x4.x + vr[0][k][1]*x4.y + vr[0][k][2]*x4.z + vr[0][k][3]*x4.w;
                    acc1 += vr[1][k][0]*x4.x + vr[1][k][1]*x4.y + vr[1][k][2]*x4.z + vr[1][k][3]*x4.w;
                    acc2 += vr[2][k][0]*x4.x + vr[2][k][1]*x4.y + vr[2][k][2]*x4.z + vr[2][k][3]*x4.w;
                    acc3 += vr[3][k][0]*x4.x + vr[3][k][1]*x4.y + vr[3][k][2]*x4.z + vr[3][k][3]*x4.w;
                }
                #pragma unroll
                for (int off = 32; off > 0; off >>= 1) {
                    acc0 += __shfl_xor(acc0, off, 64);
                    acc1 += __shfl_xor(acc1, off, 64);
                    acc2 += __shfl_xor(acc2, off, 64);
                    acc3 += __shfl_xor(acc3, off, 64);
                }
                if (lane == 0) {
                    f32x4 ig4; ig4.x = acc0; ig4.y = acc1; ig4.z = acc2; ig4.w = acc3;
                    *(f32x4*)&ig_lds[tb + j][wave * 4] = ig4;
                }
            }
            __syncthreads();
        }
    }

    float u_reg[4][8][4];
    #pragma unroll
    for (int q = 0; q < 4; ++q)
        #pragma unroll
        for (int k = 0; k < 8; ++k)
            #pragma unroll
            for (int i = 0; i < 4; ++i) u_reg[q][k][i] = 0.f;

    for (int b = 0; b < BBASIS; ++b) {
        const float ab = a[b] * inv_s;
        #pragma unroll
        for (int q = 0; q < 4; ++q) {
            const f32x4* wrow = (const f32x4*)(W + ((size_t)b * HDIM + (size_t)(r0 + q)) * HDIM);
            #pragma unroll
            for (int k = 0; k < 8; ++k) {
                f32x4 w4 = wrow[lane + 64 * k];
                u_reg[q][k][0] += ab * w4.x;
                u_reg[q][k][1] += ab * w4.y;
                u_reg[q][k][2] += ab * w4.z;
                u_reg[q][k][3] += ab * w4.w;
            }
        }
    }
    float bias4[4];
    #pragma unroll
    for (int q = 0; q < 4; ++q) bias4[q] = bias[r0 + q];

    h_lds[0][tid] = 0.f; h_lds[0][tid + 512] = 0.f;
    h_lds[0][tid + 1024] = 0.f; h_lds[0][tid + 1536] = 0.f;
    __syncthreads();

    int cur = 0;
    for (int t = 0; t < TSTEPS; ++t) {
        float acc0 = 0.f, acc1 = 0.f, acc2 = 0.f, acc3 = 0.f;
        #pragma unroll
        for (int k = 0; k < 8; ++k) {
            const f32x4 h4 = ((const f32x4*)h_lds[cur])[lane + 64 * k];
            acc0 += u_reg[0][k][0]*h4.x + u_reg[0][k][1]*h4.y + u_reg[0][k][2]*h4.z + u_reg[0][k][3]*h4.w;
            acc1 += u_reg[1][k][0]*h4.x + u_reg[1][k][1]*h4.y + u_reg[1][k][2]*h4.z + u_reg[1][k][3]*h4.w;
            acc2 += u_reg[2][k][0]*h4.x + u_reg[2][k][1]*h4.y + u_reg[2][k][2]*h4.z + u_reg[2][k][3]*h4.w;
            acc3 += u_reg[3][k][0]*h4.x + u_reg[3][k][1]*h4.y + u_reg[3][k][2]*h4.z + u_reg[3][k][3]*h4.w;
        }
        #pragma unroll
        for (int off = 32; off > 0; off >>= 1) {
            acc0 += __shfl_xor(acc0, off, 64);
            acc1 += __shfl_xor(acc1, off, 64);
            acc2 += __shfl_xor(acc2, off, 64);
            acc3 += __shfl_xor(acc3, off, 64);
        }
        float* hg = hbuf + (size_t)(t + 1) * HDIM;
        if (lane == 0) {
            const f32x4 ig4 = *(const f32x4*)&ig_lds[t][wave * 4];
            f32x4 hv;
            hv.x = tanhf(acc0 + ig4.x + bias4[0]);
            hv.y = tanhf(acc1 + ig4.y + bias4[1]);
            hv.z = tanhf(acc2 + ig4.z + bias4[2]);
            hv.w = tanhf(acc3 + ig4.w + bias4[3]);
            store_coherent_f4(hg + r0, hv);
        }
        const float* pp = hg + 4 * tid;
        f32x4 hq = load_coherent_f4(pp);
        const unsigned s = 0xFFFFFFFFu;
        while ((__float_as_uint(hq.x) == s) | (__float_as_uint(hq.y) == s) |
               (__float_as_uint(hq.z) == s) | (__float_as_uint(hq.w) == s)) {
            __builtin_amdgcn_s_sleep(1);
            hq = load_coherent_f4(pp);
        }
        const int nxt = cur ^ 1;
        *(f32x4*)&h_lds[nxt][4 * tid] = hq;
        __syncthreads();
        cur = nxt;
    }

    {
        float acc0 = 0.f, acc1 = 0.f, acc2 = 0.f, acc3 = 0.f;
        const f32x4* f0 = (const f32x4*)(fc_w + (size_t)(r0 + 0) * HDIM);
        const f32x4* f1 = (const f32x4*)(fc_w + (size_t)(r0 + 1) * HDIM);
        const f32x4* f2 = (const f32x4*)(fc_w + (size_t)(r0 + 2) * HDIM);
        const f32x4* f3 = (const f32x4*)(fc_w + (size_t)(r0 + 3) * HDIM);
        #pragma unroll
        for (int k = 0; k < 8; ++k) {
            const f32x4 h4 = ((const f32x4*)h_lds[cur])[lane + 64 * k];
            f32x4 w0 = f0[lane + 64 * k];
            f32x4 w1 = f1[lane + 64 * k];
            f32x4 w2 = f2[lane + 64 * k];
            f32x4 w3 = f3[lane + 64 * k];
            acc0 += w0.x*h4.x + w0.y*h4.y + w0.z*h4.z + w0.w*h4.w;
            acc1 += w1.x*h4.x + w1.y*h4.y + w1.z*h4.z + w1.w*h4.w;
            acc2 += w2.x*h4.x + w2.y*h4.y + w2.z*h4.z + w2.w*h4.w;
            acc3 += w3.x*h4.x + w3.y*h4.y + w3.z*h4.z + w3.w*h4.w;
        }
        #pragma unroll
        for (int off = 32; off > 0; off >>= 1) {
            acc0 += __shfl_xor(acc0, off, 64);
            acc1 += __shfl_xor(acc1, off, 64);
            acc2 += __shfl_xor(acc2, off, 64);
            acc3 += __shfl_xor(acc3, off, 64);
        }
        if (lane == 0) {
            f32x4 o4;
            o4.x = 1.f / (1.f + expf(-(acc0 + fc_b[r0 + 0])));
            o4.y = 1.f / (1.f + expf(-(acc1 + fc_b[r0 + 1])));
            o4.z = 1.f / (1.f + expf(-(acc2 + fc_b[r0 + 2])));
            o4.w = 1.f / (1.f + expf(-(acc3 + fc_b[r0 + 3])));
            *(f32x4*)&out[r0] = o4;
        }
    }
}

extern "C" void kernel_launch(void* const* d_in, const int* in_sizes, int n_in,
                              void* d_out, int out_size, void* d_ws, size_t ws_size,
                              hipStream_t stream)
{
    const float* x      = (const float*)d_in[0];
    const float* W      = (const float*)d_in[1];
    const float* alphas = (const float*)d_in[2];
    const float* bias   = (const float*)d_in[3];
    const float* v      = (const float*)d_in[4];
    const float* fc_w   = (const float*)d_in[5];
    const float* fc_b   = (const float*)d_in[6];
    const int*   ai     = (const int*)d_in[7];
    float* out = (float*)d_out;

    // workspace layout (split path)
    const size_t RING_BYTES = (size_t)RING_D * NR * HDIM * sizeof(float);  // 256 KB
    const size_t IG_OFF     = 0x80000;                                      // 512 KB
    const size_t U_OFF      = IG_OFF + 0x200000;                            // +2 MB
    const size_t U_BYTES    = (size_t)HDIM * HDIM * sizeof(float);          // 16 MB
    const size_t NEED       = U_OFF + U_BYTES;                              // ~18.5 MB

    if (ws_size >= NEED) {
        float* ring = (float*)d_ws;
        float* ig_g = (float*)((char*)d_ws + IG_OFF);
        float* u_g  = (float*)((char*)d_ws + U_OFF);
        // zero the ring each launch: 0.0 fails both parity bands -> clean start
        // (intra-launch reuse is protected by the alternating band tag).
        hipMemsetAsync(d_ws, 0, RING_BYTES, stream);
        prep_kernel<<<256, 256, 0, stream>>>(x, W, alphas, v, ai, u_g, ig_g);
        scan_kernel<<<64, 512, 0, stream>>>(bias, fc_w, fc_b, out, u_g, ig_g, (float*)ring);
    } else {
        // fallback: R5 single kernel with sentinel slots
        float* hbuf = (float*)d_ws;
        const size_t hbuf_bytes = (size_t)(TSTEPS + 1) * HDIM * sizeof(float);
        hipMemsetAsync(d_ws, 0xFF, hbuf_bytes, stream);
        elman_scan_self<<<64, 512, 0, stream>>>(x, W, alphas, bias, v, fc_w, fc_b,
                                                ai, out, hbuf);
    }
}